// Round 16
// baseline (862.203 us; speedup 1.0000x reference)
//
#include <hip/hip_runtime.h>
#include <math.h>
#include <stdint.h>

#define Bz 64
#define Tz 32
#define Ez 64
#define Hz 256
#define Vz 32000
#define KTOT 320

typedef unsigned long long u64;
typedef unsigned int u32;

__device__ __forceinline__ u32 map_f32(float f) {
  u32 u = __float_as_uint(f);
  return (u & 0x80000000u) ? ~u : (u | 0x80000000u);
}

// ---------------- weight repack: P4[j][k][g] (g = i,f,o,c); zero key bufs ----------------
// (byte-identical to round 12/15's passing k_prep)
__global__ void k_prep(const float* __restrict__ Wi, const float* __restrict__ Ui,
                       const float* __restrict__ Wf, const float* __restrict__ Uf,
                       const float* __restrict__ Wog, const float* __restrict__ Uog,
                       const float* __restrict__ Wc, const float* __restrict__ Uc,
                       float* __restrict__ P4, u64* __restrict__ key) {
  int j = blockIdx.x;        // 0..255
  int k = threadIdx.x;       // 0..319
  float g0, g1, g2, g3;
  if (k < Ez) {
    g0 = Wi[k*Hz + j]; g1 = Wf[k*Hz + j]; g2 = Wog[k*Hz + j]; g3 = Wc[k*Hz + j];
  } else {
    int kk = k - Ez;
    g0 = Ui[kk*Hz + j]; g1 = Uf[kk*Hz + j]; g2 = Uog[kk*Hz + j]; g3 = Uc[kk*Hz + j];
  }
  float* p = P4 + ((size_t)j*KTOT + k)*4;
  p[0] = g0; p[1] = g1; p[2] = g2; p[3] = g3;
  if (j == 0 && k < 2*Bz) key[k] = 0ull;
}

// ---------------- per-step LSTM cell: 64 blocks x 512 thr --------------------------------
// (byte-identical to round 12/15's passing k_gates)
__global__ __launch_bounds__(512) void k_gates(
    int t, const int* __restrict__ gnp,
    const int* __restrict__ input_x, const int* __restrict__ start_tok,
    const float* __restrict__ emb, const float* __restrict__ P4,
    const float* __restrict__ bi_, const float* __restrict__ bf_,
    const float* __restrict__ bog_, const float* __restrict__ bc_,
    const float* __restrict__ hT_in, float* __restrict__ hT_out,
    float* __restrict__ cT,
    const u64* __restrict__ key_prev, u64* __restrict__ key_cur,
    int* __restrict__ out) {
  extern __shared__ float sm[];
  float* xh = sm;                        // 20480 f : [320][64] transposed
  float* pw = sm + 20480;                // 5120 f  : 4 j x 1280
  float* sc = sm + 25600;                // 1024 f  : merge
  int*   tok_s = (int*)(sm + 26624);     // 64

  int tid = threadIdx.x;
  int blk = blockIdx.x;
  int gn = *gnp;

  if (tid < Bz) {
    int b = tid, tk;
    if (t == 0)          tk = start_tok[b];
    else if (t - 1 < gn) tk = input_x[b*Tz + (t-1)];
    else                 tk = (int)(~(u32)(key_prev[b] & 0xFFFFFFFFull));
    tok_s[b] = tk;
    if (blk == 0 && t > 0) out[b*Tz + (t-1)] = tk;
  }
  if (blk == 0 && tid >= 64 && tid < 64 + Bz) key_cur[tid - 64] = 0ull;
  __syncthreads();

  {
    int b = tid & 63, part = tid >> 6;
    const float4* e4 = (const float4*)(emb + (size_t)tok_s[b]*Ez + part*8);
    float4 v0 = e4[0], v1 = e4[1];
    int k0 = part*8;
    xh[(k0+0)*Bz + b] = v0.x; xh[(k0+1)*Bz + b] = v0.y;
    xh[(k0+2)*Bz + b] = v0.z; xh[(k0+3)*Bz + b] = v0.w;
    xh[(k0+4)*Bz + b] = v1.x; xh[(k0+5)*Bz + b] = v1.y;
    xh[(k0+6)*Bz + b] = v1.z; xh[(k0+7)*Bz + b] = v1.w;
  }
  if (t > 0) {
    const float4* s4 = (const float4*)hT_in;
    float4* d4 = (float4*)(xh + Ez*Bz);
    #pragma unroll
    for (int i = 0; i < 8; ++i) d4[tid + i*512] = s4[tid + i*512];
  }
  {
    const float* psrc = P4 + (size_t)blk*5120;
    #pragma unroll
    for (int i = 0; i < 10; ++i) pw[tid + i*512] = psrc[tid + i*512];
  }
  __syncthreads();

  int wid = tid >> 6, lane = tid & 63;
  int j4 = wid >> 1, seg = wid & 1;
  int j = blk*4 + j4;
  const float* wrow = pw + j4*1280;
  int kbeg = seg ? 160 : 0;
  int kend = (t > 0) ? (seg ? 320 : 160) : (seg ? 0 : 64);

  float ai = 0.f, af = 0.f, ao = 0.f, ac = 0.f;
  #pragma unroll 2
  for (int k = kbeg; k < kend; k += 4) {
    #pragma unroll
    for (int kk = 0; kk < 4; ++kk) {
      float4 wv = *(const float4*)(wrow + (k+kk)*4);
      float xv = xh[(k+kk)*Bz + lane];
      ai = fmaf(xv, wv.x, ai); af = fmaf(xv, wv.y, af);
      ao = fmaf(xv, wv.z, ao); ac = fmaf(xv, wv.w, ac);
    }
  }

  if (seg == 1) {
    sc[j4*256 +   0 + lane] = ai;
    sc[j4*256 +  64 + lane] = af;
    sc[j4*256 + 128 + lane] = ao;
    sc[j4*256 + 192 + lane] = ac;
  }
  __syncthreads();
  if (seg == 0) {
    ai += sc[j4*256 +   0 + lane] + bi_[j];
    af += sc[j4*256 +  64 + lane] + bf_[j];
    ao += sc[j4*256 + 128 + lane] + bog_[j];
    ac += sc[j4*256 + 192 + lane] + bc_[j];
    float gi = 1.f/(1.f + expf(-ai));
    float gf = 1.f/(1.f + expf(-af));
    float go = 1.f/(1.f + expf(-ao));
    float gc = tanhf(ac);
    float cold = (t > 0) ? cT[j*Bz + lane] : 0.f;
    float cn = gf*cold + gi*gc;
    float hn = go * tanhf(cn);
    cT[j*Bz + lane]     = cn;
    hT_out[j*Bz + lane] = hn;
  }
}

// ---------------- logits: 125 blocks x 512 thr; 2 col-tiles per block --------------------
// h staged ONCE per block (64 KB) and reused for both tiles -> broadcast bytes halved.
// Inner compute/merge/argmax byte-equivalent to round 15's passing k_logits, wrapped in
// a tile loop; merge scratch is a SEPARATE 64 KB LDS region so hLDS survives tile 0.
__global__ __launch_bounds__(512, 1) void k_logits(
    int t, const int* __restrict__ gnp,
    const float* __restrict__ hT,        // [k][b]
    const float* __restrict__ Wo, const float* __restrict__ bo,
    u64* __restrict__ key_cur) {         // 64 slots
  int gn = *gnp;
  if (t < gn) return;                    // uniform early-exit (teacher step)
  extern __shared__ float sm[];
  float* hLDS    = sm;                   // 16384 f (64 KB)
  float* scratch = sm + 16384;           // 16384 f (64 KB) merge scratch

  int tid = threadIdx.x;
  int bid = blockIdx.x;
  int wid = tid >> 6, lane = tid & 63;
  int seg = wid >> 1, chalf = wid & 1;
  int rg = lane >> 3, cg = lane & 7;

  // stage hT -> hLDS once (coalesced)
  {
    const float4* s4 = (const float4*)hT;
    float4* d4 = (float4*)hLDS;
    #pragma unroll
    for (int i = 0; i < 8; ++i) d4[tid + i*512] = s4[tid + i*512];
  }
  __syncthreads();

  const float* hp = hLDS + (seg*64)*Bz + rg*8;

  #pragma unroll 1
  for (int half = 0; half < 2; ++half) {
    int tile = bid*2 + half;

    float bo8[8];
    {
      const float4* b4 = (const float4*)(bo + tile*128 + chalf*64 + cg*8);
      float4 x = b4[0], y = b4[1];
      bo8[0]=x.x; bo8[1]=x.y; bo8[2]=x.z; bo8[3]=x.w;
      bo8[4]=y.x; bo8[5]=y.y; bo8[6]=y.z; bo8[7]=y.w;
    }

    float acc[8][8] = {};
    const float* gW = Wo + (size_t)(seg*64)*Vz + tile*128 + chalf*64 + cg*8;

    #pragma unroll 4
    for (int k = 0; k < 64; ++k) {
      float4 w0 = *(const float4*)(gW + (size_t)k*Vz);
      float4 w1 = *(const float4*)(gW + (size_t)k*Vz + 4);
      float4 h0 = *(const float4*)(hp + k*Bz);
      float4 h1 = *(const float4*)(hp + k*Bz + 4);
      float hv[8] = {h0.x,h0.y,h0.z,h0.w,h1.x,h1.y,h1.z,h1.w};
      float wv[8] = {w0.x,w0.y,w0.z,w0.w,w1.x,w1.y,w1.z,w1.w};
      #pragma unroll
      for (int r = 0; r < 8; ++r) {
        #pragma unroll
        for (int c = 0; c < 8; ++c) acc[r][c] = fmaf(hv[r], wv[c], acc[r][c]);
      }
    }

    // ---- merge k-segment partials: (seg2,seg3)->(seg0,seg1), then seg1->seg0 ----
    __syncthreads();                     // prev tile's scratch reads done; this tile ready
    if (wid >= 4) {
      float* r = scratch + (wid-4)*4096;
      #pragma unroll
      for (int i = 0; i < 64; ++i) r[i*64 + lane] = acc[i>>3][i&7];
    }
    __syncthreads();
    if (wid < 4) {
      const float* r = scratch + wid*4096;
      #pragma unroll
      for (int i = 0; i < 64; ++i) acc[i>>3][i&7] += r[i*64 + lane];
    }
    __syncthreads();
    if (wid == 2 || wid == 3) {
      float* r = scratch + (wid-2)*4096;
      #pragma unroll
      for (int i = 0; i < 64; ++i) r[i*64 + lane] = acc[i>>3][i&7];
    }
    __syncthreads();

    if (wid < 2) {
      const float* r = scratch + wid*4096;
      #pragma unroll
      for (int i = 0; i < 64; ++i) acc[i>>3][i&7] += r[i*64 + lane];

      // per-row argmax over this wave's 64 cols; first-index-wins
      int cbase = tile*128 + chalf*64 + cg*8;
      float myv = 0.f; int myi = 0;
      #pragma unroll
      for (int rr = 0; rr < 8; ++rr) {
        float bv = acc[rr][0] + bo8[0]; int bix = cbase;
        #pragma unroll
        for (int c = 1; c < 8; ++c) {
          float v = acc[rr][c] + bo8[c];
          if (v > bv) { bv = v; bix = cbase + c; }
        }
        #pragma unroll
        for (int m = 1; m < 8; m <<= 1) {
          float ov = __shfl_xor(bv, m, 64);
          int   oi = __shfl_xor(bix, m, 64);
          if (ov > bv || (ov == bv && oi < bix)) { bv = ov; bix = oi; }
        }
        if (cg == rr) { myv = bv; myi = bix; }
      }
      int row = rg*8 + cg;
      u64 kv = ((u64)map_f32(myv) << 32) | (u32)(~(u32)myi);
      atomicMax(&key_cur[row], kv);
    }
  }
}

// ---------------- final token (step T-1) -------------------------------------------------
// (byte-identical to round 12/15's passing k_final)
__global__ void k_final(const int* __restrict__ gnp, const int* __restrict__ input_x,
                        const u64* __restrict__ key_last, int* __restrict__ out) {
  int b = threadIdx.x;
  int gn = *gnp;
  int tk;
  if (Tz - 1 < gn) tk = input_x[b*Tz + Tz - 1];
  else             tk = (int)(~(u32)(key_last[b] & 0xFFFFFFFFull));
  out[b*Tz + Tz - 1] = tk;
}

extern "C" void kernel_launch(void* const* d_in, const int* in_sizes, int n_in,
                              void* d_out, int out_size, void* d_ws, size_t ws_size,
                              hipStream_t stream) {
  const int*   input_x   = (const int*)d_in[0];
  const int*   gnp       = (const int*)d_in[1];
  const int*   start_tok = (const int*)d_in[2];
  const float* emb = (const float*)d_in[3];
  const float* Wi  = (const float*)d_in[4];
  const float* Ui  = (const float*)d_in[5];
  const float* bi  = (const float*)d_in[6];
  const float* Wf  = (const float*)d_in[7];
  const float* Uf  = (const float*)d_in[8];
  const float* bff = (const float*)d_in[9];
  const float* Wog = (const float*)d_in[10];
  const float* Uog = (const float*)d_in[11];
  const float* bog = (const float*)d_in[12];
  const float* Wc  = (const float*)d_in[13];
  const float* Uc  = (const float*)d_in[14];
  const float* bc  = (const float*)d_in[15];
  const float* Wo  = (const float*)d_in[16];
  const float* bo  = (const float*)d_in[17];
  int* out = (int*)d_out;

  float* wsf = (float*)d_ws;
  float* hTA = wsf;                      // 16384 f
  float* hTB = wsf + 16384;              // 16384 f
  float* cT  = wsf + 32768;              // 16384 f
  u64*   key = (u64*)(wsf + 49152);      // 128 u64 = 256 f
  float* P4  = wsf + 49152 + 256;        // 327680 f

  size_t gsm = (size_t)(20480 + 5120 + 1024 + 64) * 4;   // 106752 B
  size_t lsm = (size_t)(16384 + 16384) * 4;              // 131072 B
  hipFuncSetAttribute((const void*)k_gates,
                      hipFuncAttributeMaxDynamicSharedMemorySize, (int)gsm);
  hipFuncSetAttribute((const void*)k_logits,
                      hipFuncAttributeMaxDynamicSharedMemorySize, (int)lsm);

  k_prep<<<dim3(256), dim3(320), 0, stream>>>(Wi, Ui, Wf, Uf, Wog, Uog, Wc, Uc, P4, key);

  for (int t = 0; t < Tz; ++t) {
    const float* hT_in  = (t & 1) ? hTA : hTB;
    float*       hT_out = (t & 1) ? hTB : hTA;
    const u64* key_prev = key + ((t + 1) & 1) * Bz;
    u64*       key_cur  = key + (t & 1) * Bz;
    k_gates<<<dim3(64), dim3(512), gsm, stream>>>(
        t, gnp, input_x, start_tok, emb, P4, bi, bff, bog, bc,
        hT_in, hT_out, cT, key_prev, key_cur, out);
    k_logits<<<dim3(125), dim3(512), lsm, stream>>>(
        t, gnp, hT_out, Wo, bo, key_cur);
  }
  k_final<<<dim3(1), dim3(64), 0, stream>>>(
      gnp, input_x, key + ((Tz - 1) & 1) * Bz, out);
}

// Round 17
// 738.031 us; speedup vs baseline: 1.1682x; 1.1682x over previous
//
#include <hip/hip_runtime.h>
#include <math.h>
#include <stdint.h>

#define Bz 64
#define Tz 32
#define Ez 64
#define Hz 256
#define Vz 32000
#define KTOT 320

typedef unsigned long long u64;
typedef unsigned int u32;

__device__ __forceinline__ u32 map_f32(float f) {
  u32 u = __float_as_uint(f);
  return (u & 0x80000000u) ? ~u : (u | 0x80000000u);
}

// ---------------- weight repack: P4[j][k][g] (g = i,f,o,c); zero key bufs ----------------
// (byte-identical to round 12/15's passing k_prep)
__global__ void k_prep(const float* __restrict__ Wi, const float* __restrict__ Ui,
                       const float* __restrict__ Wf, const float* __restrict__ Uf,
                       const float* __restrict__ Wog, const float* __restrict__ Uog,
                       const float* __restrict__ Wc, const float* __restrict__ Uc,
                       float* __restrict__ P4, u64* __restrict__ key) {
  int j = blockIdx.x;        // 0..255
  int k = threadIdx.x;       // 0..319
  float g0, g1, g2, g3;
  if (k < Ez) {
    g0 = Wi[k*Hz + j]; g1 = Wf[k*Hz + j]; g2 = Wog[k*Hz + j]; g3 = Wc[k*Hz + j];
  } else {
    int kk = k - Ez;
    g0 = Ui[kk*Hz + j]; g1 = Uf[kk*Hz + j]; g2 = Uog[kk*Hz + j]; g3 = Uc[kk*Hz + j];
  }
  float* p = P4 + ((size_t)j*KTOT + k)*4;
  p[0] = g0; p[1] = g1; p[2] = g2; p[3] = g3;
  if (j == 0 && k < 2*Bz) key[k] = 0ull;
}

// ---------------- Wo tiling: Wt[tile][k][128] contiguous 128 KB per col-tile -------------
// One-time repack so each logits block streams a LINEAR 128 KB (DRAM-page friendly).
__global__ __launch_bounds__(512) void wt_prep(const float* __restrict__ Wo,
                                               float* __restrict__ Wt) {
  int bid = blockIdx.x, tid = threadIdx.x;
  const float* src = Wo + bid*128;
  float* dst = Wt + (size_t)bid*32768;
  for (int idx = tid; idx < 32768; idx += 512) {
    int k = idx >> 7, c = idx & 127;
    dst[idx] = src[(size_t)k*Vz + c];
  }
}

// ---------------- per-step LSTM cell: 64 blocks x 512 thr --------------------------------
// (byte-identical to round 12/15's passing k_gates)
__global__ __launch_bounds__(512) void k_gates(
    int t, const int* __restrict__ gnp,
    const int* __restrict__ input_x, const int* __restrict__ start_tok,
    const float* __restrict__ emb, const float* __restrict__ P4,
    const float* __restrict__ bi_, const float* __restrict__ bf_,
    const float* __restrict__ bog_, const float* __restrict__ bc_,
    const float* __restrict__ hT_in, float* __restrict__ hT_out,
    float* __restrict__ cT,
    const u64* __restrict__ key_prev, u64* __restrict__ key_cur,
    int* __restrict__ out) {
  extern __shared__ float sm[];
  float* xh = sm;                        // 20480 f : [320][64] transposed
  float* pw = sm + 20480;                // 5120 f  : 4 j x 1280
  float* sc = sm + 25600;                // 1024 f  : merge
  int*   tok_s = (int*)(sm + 26624);     // 64

  int tid = threadIdx.x;
  int blk = blockIdx.x;
  int gn = *gnp;

  if (tid < Bz) {
    int b = tid, tk;
    if (t == 0)          tk = start_tok[b];
    else if (t - 1 < gn) tk = input_x[b*Tz + (t-1)];
    else                 tk = (int)(~(u32)(key_prev[b] & 0xFFFFFFFFull));
    tok_s[b] = tk;
    if (blk == 0 && t > 0) out[b*Tz + (t-1)] = tk;
  }
  if (blk == 0 && tid >= 64 && tid < 64 + Bz) key_cur[tid - 64] = 0ull;
  __syncthreads();

  {
    int b = tid & 63, part = tid >> 6;
    const float4* e4 = (const float4*)(emb + (size_t)tok_s[b]*Ez + part*8);
    float4 v0 = e4[0], v1 = e4[1];
    int k0 = part*8;
    xh[(k0+0)*Bz + b] = v0.x; xh[(k0+1)*Bz + b] = v0.y;
    xh[(k0+2)*Bz + b] = v0.z; xh[(k0+3)*Bz + b] = v0.w;
    xh[(k0+4)*Bz + b] = v1.x; xh[(k0+5)*Bz + b] = v1.y;
    xh[(k0+6)*Bz + b] = v1.z; xh[(k0+7)*Bz + b] = v1.w;
  }
  if (t > 0) {
    const float4* s4 = (const float4*)hT_in;
    float4* d4 = (float4*)(xh + Ez*Bz);
    #pragma unroll
    for (int i = 0; i < 8; ++i) d4[tid + i*512] = s4[tid + i*512];
  }
  {
    const float* psrc = P4 + (size_t)blk*5120;
    #pragma unroll
    for (int i = 0; i < 10; ++i) pw[tid + i*512] = psrc[tid + i*512];
  }
  __syncthreads();

  int wid = tid >> 6, lane = tid & 63;
  int j4 = wid >> 1, seg = wid & 1;
  int j = blk*4 + j4;
  const float* wrow = pw + j4*1280;
  int kbeg = seg ? 160 : 0;
  int kend = (t > 0) ? (seg ? 320 : 160) : (seg ? 0 : 64);

  float ai = 0.f, af = 0.f, ao = 0.f, ac = 0.f;
  #pragma unroll 2
  for (int k = kbeg; k < kend; k += 4) {
    #pragma unroll
    for (int kk = 0; kk < 4; ++kk) {
      float4 wv = *(const float4*)(wrow + (k+kk)*4);
      float xv = xh[(k+kk)*Bz + lane];
      ai = fmaf(xv, wv.x, ai); af = fmaf(xv, wv.y, af);
      ao = fmaf(xv, wv.z, ao); ac = fmaf(xv, wv.w, ac);
    }
  }

  if (seg == 1) {
    sc[j4*256 +   0 + lane] = ai;
    sc[j4*256 +  64 + lane] = af;
    sc[j4*256 + 128 + lane] = ao;
    sc[j4*256 + 192 + lane] = ac;
  }
  __syncthreads();
  if (seg == 0) {
    ai += sc[j4*256 +   0 + lane] + bi_[j];
    af += sc[j4*256 +  64 + lane] + bf_[j];
    ao += sc[j4*256 + 128 + lane] + bog_[j];
    ac += sc[j4*256 + 192 + lane] + bc_[j];
    float gi = 1.f/(1.f + expf(-ai));
    float gf = 1.f/(1.f + expf(-af));
    float go = 1.f/(1.f + expf(-ao));
    float gc = tanhf(ac);
    float cold = (t > 0) ? cT[j*Bz + lane] : 0.f;
    float cn = gf*cold + gi*gc;
    float hn = go * tanhf(cn);
    cT[j*Bz + lane]     = cn;
    hT_out[j*Bz + lane] = hn;
  }
}

// ---------------- logits: 250 blocks x 512 thr; LINEAR W stream -> registers -------------
// (round 15's passing k_logits with W addressing generalized: linear Wt when available)
__global__ __launch_bounds__(512, 1) void k_logits(
    int t, const int* __restrict__ gnp,
    const float* __restrict__ hT,        // [k][b]
    const float* __restrict__ Wsrc, size_t bstride, int rstride,
    const float* __restrict__ bo,
    u64* __restrict__ key_cur) {         // 64 slots
  int gn = *gnp;
  if (t < gn) return;                    // uniform early-exit (teacher step)
  extern __shared__ float sm[];
  float* hLDS = sm;                      // 16384 f (64 KB); reused as merge scratch later

  int tid = threadIdx.x;
  int bid = blockIdx.x;
  int wid = tid >> 6, lane = tid & 63;
  int seg = wid >> 1, chalf = wid & 1;
  int rg = lane >> 3, cg = lane & 7;

  float bo8[8];
  {
    const float4* b4 = (const float4*)(bo + bid*128 + chalf*64 + cg*8);
    float4 x = b4[0], y = b4[1];
    bo8[0]=x.x; bo8[1]=x.y; bo8[2]=x.z; bo8[3]=x.w;
    bo8[4]=y.x; bo8[5]=y.y; bo8[6]=y.z; bo8[7]=y.w;
  }
  // stage hT -> hLDS (coalesced)
  {
    const float4* s4 = (const float4*)hT;
    float4* d4 = (float4*)hLDS;
    #pragma unroll
    for (int i = 0; i < 8; ++i) d4[tid + i*512] = s4[tid + i*512];
  }
  __syncthreads();

  float acc[8][8] = {};
  // per-lane W base: this block's tile, this wave's k-segment and 64-col half
  const float* gW = Wsrc + (size_t)bid*bstride + (size_t)(seg*64)*rstride
                  + chalf*64 + cg*8;
  const float* hp = hLDS + (seg*64)*Bz + rg*8;

  #pragma unroll 4
  for (int k = 0; k < 64; ++k) {
    float4 w0 = *(const float4*)(gW);
    float4 w1 = *(const float4*)(gW + 4);
    gW += rstride;
    float4 h0 = *(const float4*)(hp + k*Bz);
    float4 h1 = *(const float4*)(hp + k*Bz + 4);
    float hv[8] = {h0.x,h0.y,h0.z,h0.w,h1.x,h1.y,h1.z,h1.w};
    float wv[8] = {w0.x,w0.y,w0.z,w0.w,w1.x,w1.y,w1.z,w1.w};
    #pragma unroll
    for (int r = 0; r < 8; ++r) {
      #pragma unroll
      for (int c = 0; c < 8; ++c) acc[r][c] = fmaf(hv[r], wv[c], acc[r][c]);
    }
  }

  // ---- merge k-segment partials: (seg2,seg3) -> (seg0,seg1), then seg1 -> seg0 ----
  float* scratch = hLDS;                 // 4 regions x 4096 f (h no longer needed)
  __syncthreads();                       // all waves done reading hLDS
  if (wid >= 4) {
    float* r = scratch + (wid-4)*4096;
    #pragma unroll
    for (int i = 0; i < 64; ++i) r[i*64 + lane] = acc[i>>3][i&7];
  }
  __syncthreads();
  if (wid < 4) {
    const float* r = scratch + wid*4096;
    #pragma unroll
    for (int i = 0; i < 64; ++i) acc[i>>3][i&7] += r[i*64 + lane];
  }
  __syncthreads();
  if (wid == 2 || wid == 3) {
    float* r = scratch + (wid-2)*4096;
    #pragma unroll
    for (int i = 0; i < 64; ++i) r[i*64 + lane] = acc[i>>3][i&7];
  }
  __syncthreads();

  if (wid < 2) {
    const float* r = scratch + wid*4096;
    #pragma unroll
    for (int i = 0; i < 64; ++i) acc[i>>3][i&7] += r[i*64 + lane];

    // per-row argmax over this wave's 64 cols; first-index-wins
    int cbase = bid*128 + chalf*64 + cg*8;
    float myv = 0.f; int myi = 0;
    #pragma unroll
    for (int rr = 0; rr < 8; ++rr) {
      float bv = acc[rr][0] + bo8[0]; int bix = cbase;
      #pragma unroll
      for (int c = 1; c < 8; ++c) {
        float v = acc[rr][c] + bo8[c];
        if (v > bv) { bv = v; bix = cbase + c; }
      }
      #pragma unroll
      for (int m = 1; m < 8; m <<= 1) {
        float ov = __shfl_xor(bv, m, 64);
        int   oi = __shfl_xor(bix, m, 64);
        if (ov > bv || (ov == bv && oi < bix)) { bv = ov; bix = oi; }
      }
      if (cg == rr) { myv = bv; myi = bix; }
    }
    int row = rg*8 + cg;
    u64 kv = ((u64)map_f32(myv) << 32) | (u32)(~(u32)myi);
    atomicMax(&key_cur[row], kv);
  }
}

// ---------------- final token (step T-1) -------------------------------------------------
// (byte-identical to round 12/15's passing k_final)
__global__ void k_final(const int* __restrict__ gnp, const int* __restrict__ input_x,
                        const u64* __restrict__ key_last, int* __restrict__ out) {
  int b = threadIdx.x;
  int gn = *gnp;
  int tk;
  if (Tz - 1 < gn) tk = input_x[b*Tz + Tz - 1];
  else             tk = (int)(~(u32)(key_last[b] & 0xFFFFFFFFull));
  out[b*Tz + Tz - 1] = tk;
}

extern "C" void kernel_launch(void* const* d_in, const int* in_sizes, int n_in,
                              void* d_out, int out_size, void* d_ws, size_t ws_size,
                              hipStream_t stream) {
  const int*   input_x   = (const int*)d_in[0];
  const int*   gnp       = (const int*)d_in[1];
  const int*   start_tok = (const int*)d_in[2];
  const float* emb = (const float*)d_in[3];
  const float* Wi  = (const float*)d_in[4];
  const float* Ui  = (const float*)d_in[5];
  const float* bi  = (const float*)d_in[6];
  const float* Wf  = (const float*)d_in[7];
  const float* Uf  = (const float*)d_in[8];
  const float* bff = (const float*)d_in[9];
  const float* Wog = (const float*)d_in[10];
  const float* Uog = (const float*)d_in[11];
  const float* bog = (const float*)d_in[12];
  const float* Wc  = (const float*)d_in[13];
  const float* Uc  = (const float*)d_in[14];
  const float* bc  = (const float*)d_in[15];
  const float* Wo  = (const float*)d_in[16];
  const float* bo  = (const float*)d_in[17];
  int* out = (int*)d_out;

  float* wsf = (float*)d_ws;
  float* hTA = wsf;                      // 16384 f
  float* hTB = wsf + 16384;              // 16384 f
  float* cT  = wsf + 32768;              // 16384 f
  u64*   key = (u64*)(wsf + 49152);      // 128 u64 = 256 f
  float* P4  = wsf + 49408;              // 327680 f
  float* Wt  = wsf + 377088;             // 8192000 f (32.77 MB, optional)

  bool tiled = ws_size >= (size_t)(377088 + 8192000) * 4;
  const float* Wsrc = tiled ? Wt : Wo;
  size_t bstride = tiled ? 32768 : 128;
  int    rstride = tiled ? 128 : Vz;

  size_t gsm = (size_t)(20480 + 5120 + 1024 + 64) * 4;   // 106752 B
  size_t lsm = (size_t)16384 * 4;                        // 65536 B
  hipFuncSetAttribute((const void*)k_gates,
                      hipFuncAttributeMaxDynamicSharedMemorySize, (int)gsm);
  hipFuncSetAttribute((const void*)k_logits,
                      hipFuncAttributeMaxDynamicSharedMemorySize, (int)lsm);

  k_prep<<<dim3(256), dim3(320), 0, stream>>>(Wi, Ui, Wf, Uf, Wog, Uog, Wc, Uc, P4, key);
  if (tiled)
    wt_prep<<<dim3(250), dim3(512), 0, stream>>>(Wo, Wt);

  for (int t = 0; t < Tz; ++t) {
    const float* hT_in  = (t & 1) ? hTA : hTB;
    float*       hT_out = (t & 1) ? hTB : hTA;
    const u64* key_prev = key + ((t + 1) & 1) * Bz;
    u64*       key_cur  = key + (t & 1) * Bz;
    k_gates<<<dim3(64), dim3(512), gsm, stream>>>(
        t, gnp, input_x, start_tok, emb, P4, bi, bff, bog, bc,
        hT_in, hT_out, cT, key_prev, key_cur, out);
    k_logits<<<dim3(250), dim3(512), lsm, stream>>>(
        t, gnp, hT_out, Wsrc, bstride, rstride, bo, key_cur);
  }
  k_final<<<dim3(1), dim3(64), 0, stream>>>(
      gnp, input_x, key + ((Tz - 1) & 1) * Bz, out);
}